// Round 20
// baseline (269.060 us; speedup 1.0000x reference)
//
#include <hip/hip_runtime.h>
#include <hip/hip_bf16.h>

#define N_NODES 50000
#define N_EDGES 800000
#define DIM 256      // input feature dim = K
#define QKDIM 256    // packed q|k per node (fp8: 256 B/row)
#define NB_T  391    // d0 target buckets: d0 >> 7 (128 nodes per bucket)
#define NBLK_P 391   // bin blocks (HEAD of proj_bin launch)
#define SLOT  32     // rec slots per (block,bucket); lambda 10.5 -> +6.6 sigma
#define CAPB  (NBLK_P * SLOT)   // 12512 slots per bucket
#define ITEMS (2 * N_EDGES)
#define IPB   4096   // d0 items per bin block (391*4096 >= 1.6M)
#define PROJ_BLOCKS 3125   // 50000 / 16 rows per block, exact
// pre = (0.5/H) * sum_A (q_s k_d + q_d k_s) = (full rotated 256-dot)/16

typedef __bf16 bfrag  __attribute__((ext_vector_type(8)));
typedef __bf16 bf4    __attribute__((ext_vector_type(4)));
typedef float  ffrag  __attribute__((ext_vector_type(4)));
typedef float  f2     __attribute__((ext_vector_type(2)));
typedef float  f4v    __attribute__((ext_vector_type(4)));

#define EP_PITCH 272   // epilogue LDS byte pitch (256+16)

// ---------------- proj_bin: d0 binning (blocks [0,391)) ---------------------
//                || MFMA projection (blocks [391,3516)) ----------------------
// NEW proj structure (R18 post-mortem: old 782-fat-block form was 50 us,
// latency-starved at 15.6% occupancy). Now: block = 16 rows x 256 cols,
// 4 waves each own a 64-col quarter, A-fragments loaded DIRECTLY from
// global x (2 float4 + cvt -- layout algebra-identical to the old LDS
// staging, verified), 4 waves share the 16 x-rows via L1. No main-loop LDS,
// single __syncthreads, 3125 blocks -> 12x deeper grid.
// bin = R12-proven slotted atomic-free form (LDS atomics only), bin-first.
__global__ __launch_bounds__(256) void proj_bin(
    const float* __restrict__ x,
    const float* __restrict__ Wq, const float* __restrict__ Wk,
    const float* __restrict__ bq, const float* __restrict__ bk,
    unsigned char* __restrict__ qk8,
    const int* __restrict__ d0, unsigned int* __restrict__ rec,
    unsigned char* __restrict__ cnts)
{
    __shared__ unsigned char smem[16 * EP_PITCH];   // 4.3 KB (epilogue / lcnt)
    const int tid = threadIdx.x;

    if (blockIdx.x >= NBLK_P) {
        // ================= PROJ: 16 rows x 256 cols via MFMA ===============
        const int mb   = blockIdx.x - NBLK_P;     // 0..3124
        const int wv   = tid >> 6;                // col quarter [64wv, +64)
        const int lane = tid & 63;
        const int m    = lane & 15;               // row-in-tile / col-in-tile
        const int q    = lane >> 4;               // k-subchunk 0..3
        const int row  = mb * 16 + m;             // global x row (< 50000)

        const float* xrow = x + (size_t)row * DIM;

        // W row pointers for this wave's 4 n-tiles (uniform branch per nt:
        // cols [wv*64+nt*16, +16) lie entirely in Wq (<128) or Wk (>=128))
        const float* wrow[4];
        float bias[4];
        #pragma unroll
        for (int nt = 0; nt < 4; ++nt) {
            const int col = wv * 64 + nt * 16 + m;
            wrow[nt] = (col < 128) ? (Wq + (size_t)col * DIM)
                                   : (Wk + (size_t)(col - 128) * DIM);
            bias[nt] = (col < 128) ? bq[col] : bk[col - 128];
        }

        ffrag acc[4] = {};   // one per n-tile

        #pragma unroll
        for (int ks = 0; ks < 8; ++ks) {
            const int k0 = ks * 32 + q * 8;
            // A fragment: lane holds x[row][k0..k0+8) as bf16x8
            const float4 f0 = *(const float4*)(xrow + k0);
            const float4 f1 = *(const float4*)(xrow + k0 + 4);
            bfrag a;
            a[0] = (__bf16)f0.x; a[1] = (__bf16)f0.y;
            a[2] = (__bf16)f0.z; a[3] = (__bf16)f0.w;
            a[4] = (__bf16)f1.x; a[5] = (__bf16)f1.y;
            a[6] = (__bf16)f1.z; a[7] = (__bf16)f1.w;
            #pragma unroll
            for (int nt = 0; nt < 4; ++nt) {
                const float4 g0 = *(const float4*)(wrow[nt] + k0);
                const float4 g1 = *(const float4*)(wrow[nt] + k0 + 4);
                bfrag b;
                b[0] = (__bf16)g0.x; b[1] = (__bf16)g0.y;
                b[2] = (__bf16)g0.z; b[3] = (__bf16)g0.w;
                b[4] = (__bf16)g1.x; b[5] = (__bf16)g1.y;
                b[6] = (__bf16)g1.z; b[7] = (__bf16)g1.w;
                acc[nt] = __builtin_amdgcn_mfma_f32_16x16x32_bf16(a, b, acc[nt], 0, 0, 0);
            }
        }

        // ---- epilogue: fp8-encode via LDS transpose -> coalesced stores ----
        // C/D layout (m89/m91-verified): col = lane&15, row = (lane>>4)*4 + r
        unsigned char* ep = smem;   // [16][EP_PITCH]
        #pragma unroll
        for (int nt = 0; nt < 4; ++nt) {
            const int col = wv * 64 + nt * 16 + m;
            #pragma unroll
            for (int r = 0; r < 4; ++r) {
                const int rl = q * 4 + r;          // row in 16-row tile
                const float v = acc[nt][r] + bias[nt];
                const int pk = __builtin_amdgcn_cvt_pk_fp8_f32(v, v, 0, false);
                ep[rl * EP_PITCH + col] = (unsigned char)(pk & 0xFF);
            }
        }
        __syncthreads();
        {
            const int rl = tid >> 4;               // 0..15
            const int ch = tid & 15;               // 16-B chunk
            const uint4 t0 = *(const uint4*)(ep + rl * EP_PITCH + ch * 16);
            *(uint4*)(qk8 + (size_t)(mb * 16 + rl) * QKDIM + ch * 16) = t0;
        }
        return;
    }

    // ================= BIN: slotted d0 binning, zero global atomics ========
    int* lcnt = (int*)smem;                    // 391 ints (fits 4.3 KB)
    const int pb = blockIdx.x;                 // 0..390

    for (int b = tid; b < NB_T; b += 256) lcnt[b] = 0;
    __syncthreads();
    const int base = pb * IPB;
    int tg[16];
    #pragma unroll
    for (int r = 0; r < 16; ++r) {
        const int i = base + r * 256 + tid;
        tg[r] = (i < ITEMS) ? d0[i] : -1;
        if (tg[r] >= 0) atomicAdd(&lcnt[tg[r] >> 7], 1);
    }
    __syncthreads();
    for (int b = tid; b < NB_T; b += 256) {
        const int c = lcnt[b];
        cnts[(size_t)pb * NB_T + b] = (unsigned char)(c < SLOT ? c : SLOT);
        lcnt[b] = 0;
    }
    __syncthreads();
    #pragma unroll
    for (int r = 0; r < 16; ++r) {
        if (tg[r] >= 0) {
            const int i = base + r * 256 + tid;
            const int b = tg[r] >> 7;
            const int off = atomicAdd(&lcnt[b], 1);
            if (off < SLOT)
                rec[(size_t)b * CAPB + pb * SLOT + off] =
                    ((unsigned int)(tg[r] & 127) << 20) | (unsigned int)(i >> 1);
        }
    }
}

// ---------------- edge_compute: PURE R9 known-good (42.6 us) ----------------
// 4 lanes/edge, 16 edges/wave. Load i: lane j reads src bytes 64i+16j (one
// 64B line per group-instr); dst line ((i+2)&3), offset 16j (the (t+128)&255
// q|k rotation). NO atomics, no fused work.  [R4/R9-verified]
__global__ __launch_bounds__(256) void edge_compute(
    const unsigned char* __restrict__ qk8,
    const int* __restrict__ edge_index,   // [2][E]
    float* __restrict__ out)              // writes diagA1 = out[N..N+E)
{
    const int wave = (blockIdx.x * blockDim.x + threadIdx.x) >> 6;
    const int lane = threadIdx.x & 63;
    const int g = lane >> 2;
    const int j = lane & 3;
    const int e = wave * 16 + g;          // 800000 = 50000*16, no tail

    const int src = __builtin_nontemporal_load(edge_index + e);
    const int dst = __builtin_nontemporal_load(edge_index + N_EDGES + e);

    const uint4* rs = (const uint4*)(qk8 + (size_t)src * QKDIM);
    const uint4* rd = (const uint4*)(qk8 + (size_t)dst * QKDIM);

    uint4 a[4], b[4];
    #pragma unroll
    for (int i = 0; i < 4; ++i) a[i] = rs[4 * i + j];
    #pragma unroll
    for (int i = 0; i < 4; ++i) b[i] = rd[4 * ((i + 2) & 3) + j];

    f2 acc = {0.f, 0.f};
    #pragma unroll
    for (int i = 0; i < 4; ++i) {
        const unsigned int* ua = (const unsigned int*)&a[i];
        const unsigned int* ub = (const unsigned int*)&b[i];
        #pragma unroll
        for (int t = 0; t < 4; ++t) {
            const f2 x0 = __builtin_amdgcn_cvt_pk_f32_fp8(ua[t], false);
            const f2 y0 = __builtin_amdgcn_cvt_pk_f32_fp8(ub[t], false);
            const f2 x1 = __builtin_amdgcn_cvt_pk_f32_fp8(ua[t], true);
            const f2 y1 = __builtin_amdgcn_cvt_pk_f32_fp8(ub[t], true);
            acc += x0 * y0;
            acc += x1 * y1;
        }
    }
    float p = acc[0] + acc[1];
    p += __shfl_xor(p, 1, 64);
    p += __shfl_xor(p, 2, 64);

    if (j == 0)
        out[N_NODES + e] = __expf(p * 0.0625f);   // /16 = 0.5 * mean over 8 heads
}

// ---------------- phase_scatter: slotted rec + per-WAVE LDS accumulators ----
// Block b owns nodes [128b,128b+128): scans 391 sub-chunks x 32 slots guided
// by count bytes; gathers val[e] from L2-resident diagA1; LDS atomics;
// unique-writer stores. No global atomics, no pre-zeroing.  [R12-proven]
__global__ __launch_bounds__(1024) void phase_scatter(
    const unsigned int* __restrict__ rec, const unsigned char* __restrict__ cnts,
    float* __restrict__ out)
{
    __shared__ float acc[16][128];
    __shared__ unsigned char lc[NBLK_P];
    const int b = blockIdx.x;
    const int tid = threadIdx.x;
    const int wid = tid >> 6;
    for (int i = tid; i < 16 * 128; i += 1024) ((float*)acc)[i] = 0.f;
    if (tid < NBLK_P) lc[tid] = cnts[(size_t)tid * NB_T + b];
    __syncthreads();

    const unsigned int* rb = rec + (size_t)b * CAPB;
    for (int s = tid; s < CAPB; s += 1024) {
        const int blk = s >> 5;           // SLOT = 32
        const int off = s & (SLOT - 1);
        if (off < (int)lc[blk]) {
            const unsigned int r = rb[s];
            const float v = out[N_NODES + (r & 0xFFFFF)];
            atomicAdd(&acc[wid][r >> 20], v);
        }
    }
    __syncthreads();

    if (tid < 128) {
        float s = 0.f;
        #pragma unroll
        for (int w = 0; w < 16; ++w) s += acc[w][tid];
        const int n = b * 128 + tid;
        if (n < N_NODES) out[n] = s;
    }
}

// ---------------- fallback: edge + direct atomics (ws too small) ------------
__global__ __launch_bounds__(256) void edge_atomic(
    const unsigned char* __restrict__ qk8,
    const int* __restrict__ edge_index, const int* __restrict__ d0,
    float* __restrict__ out)
{
    const int wave = (blockIdx.x * blockDim.x + threadIdx.x) >> 6;
    const int lane = threadIdx.x & 63;
    const int g = lane >> 2, j = lane & 3;
    const int e = wave * 16 + g;

    const int src = edge_index[e];
    const int dst = edge_index[N_EDGES + e];

    const uint4* rs = (const uint4*)(qk8 + (size_t)src * QKDIM);
    const uint4* rd = (const uint4*)(qk8 + (size_t)dst * QKDIM);

    uint4 a[4], b[4];
    #pragma unroll
    for (int i = 0; i < 4; ++i) a[i] = rs[4 * i + j];
    #pragma unroll
    for (int i = 0; i < 4; ++i) b[i] = rd[4 * ((i + 2) & 3) + j];

    f2 acc = {0.f, 0.f};
    #pragma unroll
    for (int i = 0; i < 4; ++i) {
        const unsigned int* ua = (const unsigned int*)&a[i];
        const unsigned int* ub = (const unsigned int*)&b[i];
        #pragma unroll
        for (int t = 0; t < 4; ++t) {
            const f2 x0 = __builtin_amdgcn_cvt_pk_f32_fp8(ua[t], false);
            const f2 y0 = __builtin_amdgcn_cvt_pk_f32_fp8(ub[t], false);
            const f2 x1 = __builtin_amdgcn_cvt_pk_f32_fp8(ua[t], true);
            const f2 y1 = __builtin_amdgcn_cvt_pk_f32_fp8(ub[t], true);
            acc += x0 * y0;
            acc += x1 * y1;
        }
    }
    float p = acc[0] + acc[1];
    p += __shfl_xor(p, 1, 64);
    p += __shfl_xor(p, 2, 64);

    if (j < 2) {
        const float val = __expf(p * 0.0625f);
        if (j == 0) out[N_NODES + e] = val;
        atomicAdd(&out[d0[2 * e + j]], val);
    }
}

// ===================== launcher: 3 dispatches ===============================

extern "C" void kernel_launch(void* const* d_in, const int* in_sizes, int n_in,
                              void* d_out, int out_size, void* d_ws, size_t ws_size,
                              hipStream_t stream) {
    const float* x  = (const float*)d_in[0];
    const float* Wq = (const float*)d_in[1];
    const float* bq = (const float*)d_in[2];
    const float* Wk = (const float*)d_in[3];
    const float* bk = (const float*)d_in[4];
    const int* edge_index = (const int*)d_in[5];
    const int* d0 = (const int*)d_in[6] + 2 * N_EDGES;  // row 1 of d0_index
    float* out = (float*)d_out;

    char* w = (char*)d_ws;
    unsigned char* qk8 = (unsigned char*)w;  w += (size_t)N_NODES * QKDIM;   // 12.8 MB
    unsigned int* rec = (unsigned int*)w;    w += (size_t)NB_T * CAPB * 4;   // 19.6 MB
    unsigned char* cnts = (unsigned char*)w; w += (size_t)NBLK_P * NB_T;     // 150 KB

    const size_t need = (size_t)(w - (char*)d_ws);
    const int use_bin = (ws_size >= need) ? 1 : 0;

    if (use_bin) {
        proj_bin<<<NBLK_P + PROJ_BLOCKS, 256, 0, stream>>>(
            x, Wq, Wk, bq, bk, qk8, d0, rec, cnts);
        edge_compute<<<N_EDGES / 64, 256, 0, stream>>>(qk8, edge_index, out);
        phase_scatter<<<NB_T, 1024, 0, stream>>>(rec, cnts, out);
    } else {
        hipMemsetAsync(out, 0, N_NODES * sizeof(float), stream);
        proj_bin<<<NBLK_P + PROJ_BLOCKS, 256, 0, stream>>>(
            x, Wq, Wk, bq, bk, qk8, d0, rec, cnts);
        edge_atomic<<<N_EDGES / 64, 256, 0, stream>>>(qk8, edge_index, d0, out);
    }
}

// Round 21
// 195.314 us; speedup vs baseline: 1.3776x; 1.3776x over previous
//
#include <hip/hip_runtime.h>
#include <hip/hip_bf16.h>

#define N_NODES 50000
#define N_EDGES 800000
#define DIM 256      // input feature dim = K
#define QKDIM 256    // packed q|k per node (fp8: 256 B/row)
#define NB_T  391    // d0 target buckets: d0 >> 7 (128 nodes per bucket)
#define NBLK_P 391
#define SLOT  32     // rec slots per (block,bucket); lambda 10.5 -> +6.6 sigma
#define CAPB  (NBLK_P * SLOT)   // 12512 slots per bucket
#define ITEMS (2 * N_EDGES)
#define IPB   4096
// pre = (0.5/H) * sum_A (q_s k_d + q_d k_s) = (full rotated 256-dot)/16

typedef __bf16 bfrag  __attribute__((ext_vector_type(8)));
typedef __bf16 bf4    __attribute__((ext_vector_type(4)));
typedef float  ffrag  __attribute__((ext_vector_type(4)));
typedef float  f2     __attribute__((ext_vector_type(2)));
typedef float  f4v    __attribute__((ext_vector_type(4)));

#define EP_PITCH 272   // epilogue LDS byte pitch (256+16)

// ---------------- prep_bin: W convert + d0 binning, ZERO global atomics -----
// [R12-proven] Deterministic sub-slot layout: block blk owns
// rec[b*CAPB + blk*32 .. +32) in every bucket b; per-cell count stored as a
// clamped byte. LDS atomics only.
__global__ __launch_bounds__(512) void prep_bin(
    const float* __restrict__ Wq, const float* __restrict__ Wk,
    __bf16* __restrict__ Wb,
    const int* __restrict__ d0, unsigned int* __restrict__ rec,
    unsigned char* __restrict__ cnts, int do_bin)
{
    __shared__ int lcnt[NB_T];
    const int tid = threadIdx.x;
    const int gtid = blockIdx.x * 512 + tid;

    // ---- W convert (first 16384 gtids cover 65536 floats) ----
    const int i4 = gtid * 4;
    if (i4 < 65536) {
        const float* s = (i4 < 32768) ? (Wq + i4) : (Wk + (i4 - 32768));
        const float4 v = *(const float4*)s;
        bf4 o;
        o[0] = (__bf16)v.x; o[1] = (__bf16)v.y; o[2] = (__bf16)v.z; o[3] = (__bf16)v.w;
        *(bf4*)(Wb + i4) = o;
    }
    if (!do_bin) return;

    for (int b = tid; b < NB_T; b += 512) lcnt[b] = 0;
    __syncthreads();
    const int base = blockIdx.x * IPB;
    int tg[8];
    #pragma unroll
    for (int r = 0; r < 8; ++r) {
        const int i = base + r * 512 + tid;
        tg[r] = (i < ITEMS) ? d0[i] : -1;
        if (tg[r] >= 0) atomicAdd(&lcnt[tg[r] >> 7], 1);
    }
    __syncthreads();
    for (int b = tid; b < NB_T; b += 512) {
        const int c = lcnt[b];
        cnts[(size_t)blockIdx.x * NB_T + b] = (unsigned char)(c < SLOT ? c : SLOT);
        lcnt[b] = 0;
    }
    __syncthreads();
    #pragma unroll
    for (int r = 0; r < 8; ++r) {
        if (tg[r] >= 0) {
            const int i = base + r * 512 + tid;
            const int b = tg[r] >> 7;
            const int off = atomicAdd(&lcnt[b], 1);
            if (off < SLOT)
                rec[(size_t)b * CAPB + blockIdx.x * SLOT + off] =
                    ((unsigned int)(tg[r] & 127) << 20) | (unsigned int)(i >> 1);
        }
    }
}

// ---------------- Projection via MFMA bf16 (R9/R12-proven, Wb path) ---------
__global__ __launch_bounds__(256) void proj_mfma(
    const float* __restrict__ x,
    const __bf16* __restrict__ Wb,
    const float* __restrict__ bq, const float* __restrict__ bk,
    unsigned char* __restrict__ qk8)
{
    __shared__ __bf16 As[64 * 256];   // 32 KB, fragment-order; reused by epilogue

    const int tid  = threadIdx.x;
    const int wv   = tid >> 6;
    const int lane = tid & 63;
    const int m    = lane & 15;
    const int q    = lane >> 4;
    const int mbase = blockIdx.x * 64;

    {
        const int srow = tid >> 2;
        const int c4   = tid & 3;
        int grow = mbase + srow;
        grow = grow < N_NODES ? grow : N_NODES - 1;
        const float* xp = x + (size_t)grow * DIM;
        const int mt_ = srow >> 4, m_ = srow & 15;
        #pragma unroll
        for (int i = 0; i < 16; ++i) {
            const int k = c4 * 4 + 16 * i;
            const f4v v = __builtin_nontemporal_load((const f4v*)(xp + k));
            bf4 o;
            o[0] = (__bf16)v[0]; o[1] = (__bf16)v[1];
            o[2] = (__bf16)v[2]; o[3] = (__bf16)v[3];
            const int seg = (k >> 5) * 4 + mt_;
            const int ln  = ((k >> 3) & 3) * 16 + m_;
            *(bf4*)(As + seg * 512 + ln * 8 + (k & 7)) = o;
        }
    }
    __syncthreads();

    ffrag acc[4][4] = {};

    #pragma unroll
    for (int h = 0; h < 2; ++h) {
        bfrag b[4][4];
        #pragma unroll
        for (int sp = 0; sp < 4; ++sp)
            #pragma unroll
            for (int nt = 0; nt < 4; ++nt) {
                const int col = wv * 64 + nt * 16 + m;
                b[sp][nt] = *(const bfrag*)(Wb + (size_t)col * DIM
                                            + 32 * (4 * h + sp) + 8 * q);
            }
        #pragma unroll
        for (int sp = 0; sp < 4; ++sp) {
            bfrag a[4];
            #pragma unroll
            for (int mt = 0; mt < 4; ++mt)
                a[mt] = *(const bfrag*)(As + ((4 * h + sp) * 4 + mt) * 512 + lane * 8);
            #pragma unroll
            for (int mt = 0; mt < 4; ++mt)
                #pragma unroll
                for (int nt = 0; nt < 4; ++nt)
                    acc[mt][nt] = __builtin_amdgcn_mfma_f32_16x16x32_bf16(
                                      a[mt], b[sp][nt], acc[mt][nt], 0, 0, 0);
        }
    }

    __syncthreads();
    unsigned char* ep = (unsigned char*)As;
    #pragma unroll
    for (int nt = 0; nt < 4; ++nt) {
        const int col  = wv * 64 + nt * 16 + m;
        const float bias = (col < 128) ? bq[col] : bk[col - 128];
        #pragma unroll
        for (int mt = 0; mt < 4; ++mt) {
            #pragma unroll
            for (int r = 0; r < 4; ++r) {
                const int rl = mt * 16 + q * 4 + r;
                const float v = acc[mt][nt][r] + bias;
                const int pk = __builtin_amdgcn_cvt_pk_fp8_f32(v, v, 0, false);
                ep[rl * EP_PITCH + col] = (unsigned char)(pk & 0xFF);
            }
        }
    }
    __syncthreads();
    {
        const int rl = tid >> 2;
        const int ch = tid & 3;
        const int grow = mbase + rl;
        if (grow < N_NODES) {
            const uint4* s4 = (const uint4*)(ep + rl * EP_PITCH + ch * 64);
            const uint4 t0 = s4[0], t1 = s4[1], t2 = s4[2], t3 = s4[3];
            uint4* g = (uint4*)(qk8 + (size_t)grow * QKDIM + ch * 64);
            g[0] = t0; g[1] = t1; g[2] = t2; g[3] = t3;
        }
    }
}

// ---------------- edge_compute: PURE R9 known-good (42.6 us) ----------------
// 4 lanes/edge, 16 edges/wave. Load i: lane j reads src bytes 64i+16j (one
// 64B line per group-instr); dst line ((i+2)&3), offset 16j (the (t+128)&255
// q|k rotation). NO atomics.  [R4/R9-verified]
__global__ __launch_bounds__(256) void edge_compute(
    const unsigned char* __restrict__ qk8,
    const int* __restrict__ edge_index,
    float* __restrict__ out)
{
    const int wave = (blockIdx.x * blockDim.x + threadIdx.x) >> 6;
    const int lane = threadIdx.x & 63;
    const int g = lane >> 2;
    const int j = lane & 3;
    const int e = wave * 16 + g;          // 800000 = 50000*16, no tail

    const int src = __builtin_nontemporal_load(edge_index + e);
    const int dst = __builtin_nontemporal_load(edge_index + N_EDGES + e);

    const uint4* rs = (const uint4*)(qk8 + (size_t)src * QKDIM);
    const uint4* rd = (const uint4*)(qk8 + (size_t)dst * QKDIM);

    uint4 a[4], b[4];
    #pragma unroll
    for (int i = 0; i < 4; ++i) a[i] = rs[4 * i + j];
    #pragma unroll
    for (int i = 0; i < 4; ++i) b[i] = rd[4 * ((i + 2) & 3) + j];

    f2 acc = {0.f, 0.f};
    #pragma unroll
    for (int i = 0; i < 4; ++i) {
        const unsigned int* ua = (const unsigned int*)&a[i];
        const unsigned int* ub = (const unsigned int*)&b[i];
        #pragma unroll
        for (int t = 0; t < 4; ++t) {
            const f2 x0 = __builtin_amdgcn_cvt_pk_f32_fp8(ua[t], false);
            const f2 y0 = __builtin_amdgcn_cvt_pk_f32_fp8(ub[t], false);
            const f2 x1 = __builtin_amdgcn_cvt_pk_f32_fp8(ua[t], true);
            const f2 y1 = __builtin_amdgcn_cvt_pk_f32_fp8(ub[t], true);
            acc += x0 * y0;
            acc += x1 * y1;
        }
    }
    float p = acc[0] + acc[1];
    p += __shfl_xor(p, 1, 64);
    p += __shfl_xor(p, 2, 64);

    if (j == 0)
        out[N_NODES + e] = __expf(p * 0.0625f);   // /16 = 0.5 * mean over 8 heads
}

// ---------------- phase_scatter: slotted rec + per-WAVE LDS accumulators ----
// [R12-proven] Block b owns nodes [128b,128b+128): scans 391 sub-chunks x 32
// slots guided by count bytes; gathers val[e] from L2-resident diagA1; LDS
// atomics; unique-writer stores. No global atomics, no pre-zeroing.
__global__ __launch_bounds__(1024) void phase_scatter(
    const unsigned int* __restrict__ rec, const unsigned char* __restrict__ cnts,
    float* __restrict__ out)
{
    __shared__ float acc[16][128];
    __shared__ unsigned char lc[NBLK_P];
    const int b = blockIdx.x;
    const int tid = threadIdx.x;
    const int wid = tid >> 6;
    for (int i = tid; i < 16 * 128; i += 1024) ((float*)acc)[i] = 0.f;
    if (tid < NBLK_P) lc[tid] = cnts[(size_t)tid * NB_T + b];
    __syncthreads();

    const unsigned int* rb = rec + (size_t)b * CAPB;
    for (int s = tid; s < CAPB; s += 1024) {
        const int blk = s >> 5;           // SLOT = 32
        const int off = s & (SLOT - 1);
        if (off < (int)lc[blk]) {
            const unsigned int r = rb[s];
            const float v = out[N_NODES + (r & 0xFFFFF)];
            atomicAdd(&acc[wid][r >> 20], v);
        }
    }
    __syncthreads();

    if (tid < 128) {
        float s = 0.f;
        #pragma unroll
        for (int w = 0; w < 16; ++w) s += acc[w][tid];
        const int n = b * 128 + tid;
        if (n < N_NODES) out[n] = s;
    }
}

// ---------------- fallback: edge + direct atomics (ws too small) ------------
__global__ __launch_bounds__(256) void edge_atomic(
    const unsigned char* __restrict__ qk8,
    const int* __restrict__ edge_index, const int* __restrict__ d0,
    float* __restrict__ out)
{
    const int wave = (blockIdx.x * blockDim.x + threadIdx.x) >> 6;
    const int lane = threadIdx.x & 63;
    const int g = lane >> 2, j = lane & 3;
    const int e = wave * 16 + g;

    const int src = edge_index[e];
    const int dst = edge_index[N_EDGES + e];

    const uint4* rs = (const uint4*)(qk8 + (size_t)src * QKDIM);
    const uint4* rd = (const uint4*)(qk8 + (size_t)dst * QKDIM);

    uint4 a[4], b[4];
    #pragma unroll
    for (int i = 0; i < 4; ++i) a[i] = rs[4 * i + j];
    #pragma unroll
    for (int i = 0; i < 4; ++i) b[i] = rd[4 * ((i + 2) & 3) + j];

    f2 acc = {0.f, 0.f};
    #pragma unroll
    for (int i = 0; i < 4; ++i) {
        const unsigned int* ua = (const unsigned int*)&a[i];
        const unsigned int* ub = (const unsigned int*)&b[i];
        #pragma unroll
        for (int t = 0; t < 4; ++t) {
            const f2 x0 = __builtin_amdgcn_cvt_pk_f32_fp8(ua[t], false);
            const f2 y0 = __builtin_amdgcn_cvt_pk_f32_fp8(ub[t], false);
            const f2 x1 = __builtin_amdgcn_cvt_pk_f32_fp8(ua[t], true);
            const f2 y1 = __builtin_amdgcn_cvt_pk_f32_fp8(ub[t], true);
            acc += x0 * y0;
            acc += x1 * y1;
        }
    }
    float p = acc[0] + acc[1];
    p += __shfl_xor(p, 1, 64);
    p += __shfl_xor(p, 2, 64);

    if (j < 2) {
        const float val = __expf(p * 0.0625f);
        if (j == 0) out[N_NODES + e] = val;
        atomicAdd(&out[d0[2 * e + j]], val);
    }
}

// ===================== launcher: R12/R14 proven 4-dispatch path =============

extern "C" void kernel_launch(void* const* d_in, const int* in_sizes, int n_in,
                              void* d_out, int out_size, void* d_ws, size_t ws_size,
                              hipStream_t stream) {
    const float* x  = (const float*)d_in[0];
    const float* Wq = (const float*)d_in[1];
    const float* bq = (const float*)d_in[2];
    const float* Wk = (const float*)d_in[3];
    const float* bk = (const float*)d_in[4];
    const int* edge_index = (const int*)d_in[5];
    const int* d0 = (const int*)d_in[6] + 2 * N_EDGES;  // row 1 of d0_index
    float* out = (float*)d_out;

    char* w = (char*)d_ws;
    unsigned char* qk8 = (unsigned char*)w;  w += (size_t)N_NODES * QKDIM;   // 12.8 MB
    __bf16* Wb = (__bf16*)w;                 w += 131072;                    // 128 KB
    unsigned int* rec = (unsigned int*)w;    w += (size_t)NB_T * CAPB * 4;   // 19.6 MB
    unsigned char* cnts = (unsigned char*)w; w += (size_t)NBLK_P * NB_T;     // 150 KB

    const size_t need = (size_t)(w - (char*)d_ws);
    const int use_bin = (ws_size >= need) ? 1 : 0;

    if (use_bin) {
        prep_bin<<<NBLK_P, 512, 0, stream>>>(Wq, Wk, Wb, d0, rec, cnts, 1);
        proj_mfma<<<(N_NODES + 63) / 64, 256, 0, stream>>>(x, Wb, bq, bk, qk8);
        edge_compute<<<N_EDGES / 64, 256, 0, stream>>>(qk8, edge_index, out);
        phase_scatter<<<NB_T, 1024, 0, stream>>>(rec, cnts, out);
    } else {
        hipMemsetAsync(out, 0, N_NODES * sizeof(float), stream);
        prep_bin<<<NBLK_P, 512, 0, stream>>>(Wq, Wk, Wb, d0, rec, cnts, 0);
        proj_mfma<<<(N_NODES + 63) / 64, 256, 0, stream>>>(x, Wb, bq, bk, qk8);
        edge_atomic<<<N_EDGES / 64, 256, 0, stream>>>(qk8, edge_index, d0, out);
    }
}